// Round 8
// baseline (115.928 us; speedup 1.0000x reference)
//
#include <hip/hip_runtime.h>
#include <math.h>

// VQ-VAE vector quantizer for MI355X (gfx950).
// z: [32768, 64] fp32, codebook: [1024, 64] fp32.
// Outputs (flat float32, concatenated): quantized_st [32768*64], vq_loss [1],
// indices [32768] (as float), perplexity [1].
//
// R8: R4/R6/R7 all ~40 us vq_main with MfmaUtil ~12%, VALUBusy ~16% -> ~30 us
// pure idle. Root cause: 512 blocks x 4 waves = 2 waves/SIMD; nothing hides
// latency, and intra-wave prefetch (R6/R7) proved neutral. Fix: MT=2 ->
// 1024 blocks = 4 waves/SIMD, with amdgpu_waves_per_eu(4,4) pinning the
// allocator at the 128-VGPR target so it cannot occupancy-chase to 64 regs
// and rematerialize A-frags (the R5 failure). LDS ~28 KB -> 4 blocks/CU fit.
// Numerics unchanged (3-term split-bf16 + exact fp32 recheck, margin 1e-5).

#define D 64
#define KC 1024
#define MT 2              // 16-row m-tiles per wave
#define ROWS (MT * 16)    // 32 rows per block

typedef short short8 __attribute__((ext_vector_type(8)));
typedef short short4v __attribute__((ext_vector_type(4)));
typedef float f32x4 __attribute__((ext_vector_type(4)));

__device__ __forceinline__ unsigned short f2bf(float x) {
  unsigned int u = __float_as_uint(x);
  unsigned int r = (u + 0x7fffu + ((u >> 16) & 1u)) >> 16;
  return (unsigned short)r;
}
__device__ __forceinline__ float bf2f(unsigned short h) {
  return __uint_as_float((unsigned int)h << 16);
}

// Precompute: exact fp32 code norms, split-bf16 codebook
// bsplit[k][128] = [e_hi(64) | e_lo(64)], zero hist/loss.
__global__ __launch_bounds__(256) void vq_prep(
    const float* __restrict__ cb, unsigned short* __restrict__ bsplit,
    float* __restrict__ cbn, unsigned int* __restrict__ hist,
    float* __restrict__ loss_acc) {
  const int k = blockIdx.x * 256 + threadIdx.x;  // 0..1023
  const float4* e = (const float4*)(cb + (size_t)k * D);
  unsigned short* bp = bsplit + (size_t)k * 128;
  float s0 = 0.f, s1 = 0.f, s2 = 0.f, s3 = 0.f;
#pragma unroll
  for (int i = 0; i < 16; ++i) {
    float4 v = e[i];
    s0 = fmaf(v.x, v.x, s0);
    s1 = fmaf(v.y, v.y, s1);
    s2 = fmaf(v.z, v.z, s2);
    s3 = fmaf(v.w, v.w, s3);
    unsigned short h0 = f2bf(v.x), h1 = f2bf(v.y), h2 = f2bf(v.z), h3 = f2bf(v.w);
    short4v hv = {(short)h0, (short)h1, (short)h2, (short)h3};
    short4v lv = {(short)f2bf(v.x - bf2f(h0)), (short)f2bf(v.y - bf2f(h1)),
                  (short)f2bf(v.z - bf2f(h2)), (short)f2bf(v.w - bf2f(h3))};
    *(short4v*)(bp + i * 4) = hv;
    *(short4v*)(bp + 64 + i * 4) = lv;
  }
  cbn[k] = (s0 + s1) + (s2 + s3);
  hist[k] = 0u;
  if (k == 0) loss_acc[0] = 0.f;
}

__global__ __launch_bounds__(256)
__attribute__((amdgpu_waves_per_eu(4, 4))) void vq_main(
    const float* __restrict__ z, const unsigned short* __restrict__ bsplit,
    const float* __restrict__ cbn, const float* __restrict__ cb,
    float* __restrict__ out_q, float* __restrict__ out_idx,
    unsigned int* __restrict__ hist, float* __restrict__ loss_acc) {
  // A' split-bf16 z tile: [32 rows][128 inner], stride 136 (bank-skew).
  __shared__ unsigned short Ash[ROWS * 136];
  __shared__ float srzp[ROWS * 16];
  __shared__ float srz[ROWS];
  __shared__ float candd[4][ROWS][17];  // +1 pad
  __shared__ int candk[4][ROWS][17];
  __shared__ int skf[ROWS];
  __shared__ float swav[4];

  const int tid = threadIdx.x;
  const int lane = tid & 63;
  const int wav = tid >> 6;
  const int quad = lane >> 4;
  const int col = lane & 15;
  const int rowbase = blockIdx.x * ROWS;

  // ---- prologue: load z tile (coalesced), split to bf16 hi/lo, row norms
  const float4* z4 = (const float4*)(z + (size_t)rowbase * D);
#pragma unroll
  for (int it = 0; it < ROWS / 16; ++it) {
    int f4 = it * 256 + tid;  // row*16 + (c4/4)
    int row = f4 >> 4, c4 = (f4 & 15) * 4;
    float4 v = z4[f4];
    srzp[f4] = ((v.x * v.x + v.y * v.y) + (v.z * v.z + v.w * v.w));
    unsigned short h0 = f2bf(v.x), h1 = f2bf(v.y), h2 = f2bf(v.z), h3 = f2bf(v.w);
    short4v hv = {(short)h0, (short)h1, (short)h2, (short)h3};
    short4v lv = {(short)f2bf(v.x - bf2f(h0)), (short)f2bf(v.y - bf2f(h1)),
                  (short)f2bf(v.z - bf2f(h2)), (short)f2bf(v.w - bf2f(h3))};
    *(short4v*)&Ash[row * 136 + c4] = hv;
    *(short4v*)&Ash[row * 136 + 64 + c4] = lv;
  }
  __syncthreads();
  if (tid < ROWS) {
    float s = 0.f;
#pragma unroll
    for (int i = 0; i < 16; ++i) s += srzp[tid * 16 + i];
    srz[tid] = s;
  }
  __syncthreads();

  // rz per (m-tile, reg): lane holds C rows mt*16 + quad*4 + reg
  float rzv[MT * 4];
#pragma unroll
  for (int mt = 0; mt < MT; ++mt)
#pragma unroll
    for (int reg = 0; reg < 4; ++reg)
      rzv[mt * 4 + reg] = srz[mt * 16 + quad * 4 + reg];

  // A fragments in registers: a[mt][{hi0,hi1,lo0,lo1}], 8 bf16 each.
  // A-operand layout: lane holds A[m = col][k = quad*8 + j].
  short8 a[MT][4];
#pragma unroll
  for (int mt = 0; mt < MT; ++mt) {
    const unsigned short* base = &Ash[(mt * 16 + col) * 136 + quad * 8];
    a[mt][0] = *(const short8*)(base + 0);    // z_hi k 0..31
    a[mt][1] = *(const short8*)(base + 32);   // z_hi k 32..63
    a[mt][2] = *(const short8*)(base + 64);   // z_lo k 0..31
    a[mt][3] = *(const short8*)(base + 96);   // z_lo k 32..63
  }

  float bestd[MT * 4];
  int bestk[MT * 4];
#pragma unroll
  for (int i = 0; i < MT * 4; ++i) {
    bestd[i] = 3.4e38f;
    bestk[i] = 0;
  }

  // Each wave scans 256 codes in 16 k-tiles of 16 codes, next tile's
  // B-fragments prefetched into registers.
  const int k0 = wav * 256;
  short8 nb0, nb1, nb2, nb3;
  float nen;
  {
    const unsigned short* bb = bsplit + (size_t)(k0 + col) * 128 + quad * 8;
    nb0 = *(const short8*)(bb + 0);
    nb1 = *(const short8*)(bb + 32);
    nb2 = *(const short8*)(bb + 64);
    nb3 = *(const short8*)(bb + 96);
    nen = cbn[k0 + col];
  }
  for (int kt = 0; kt < 16; ++kt) {
    const int mycode = k0 + kt * 16 + col;
    const short8 b0 = nb0, b1 = nb1, b2 = nb2, b3 = nb3;
    const float en = nen;
    if (kt < 15) {
      const unsigned short* nbb =
          bsplit + (size_t)(mycode + 16) * 128 + quad * 8;
      nb0 = *(const short8*)(nbb + 0);
      nb1 = *(const short8*)(nbb + 32);
      nb2 = *(const short8*)(nbb + 64);
      nb3 = *(const short8*)(nbb + 96);
      nen = cbn[mycode + 16];
    }

    f32x4 acc[MT];
#pragma unroll
    for (int mt = 0; mt < MT; ++mt) acc[mt] = {0.f, 0.f, 0.f, 0.f};
    // 6 products per mt, MT independent chains
#pragma unroll
    for (int mt = 0; mt < MT; ++mt)
      acc[mt] = __builtin_amdgcn_mfma_f32_16x16x32_bf16(a[mt][0], b0, acc[mt], 0, 0, 0);
#pragma unroll
    for (int mt = 0; mt < MT; ++mt)
      acc[mt] = __builtin_amdgcn_mfma_f32_16x16x32_bf16(a[mt][1], b1, acc[mt], 0, 0, 0);
#pragma unroll
    for (int mt = 0; mt < MT; ++mt)
      acc[mt] = __builtin_amdgcn_mfma_f32_16x16x32_bf16(a[mt][2], b0, acc[mt], 0, 0, 0);
#pragma unroll
    for (int mt = 0; mt < MT; ++mt)
      acc[mt] = __builtin_amdgcn_mfma_f32_16x16x32_bf16(a[mt][3], b1, acc[mt], 0, 0, 0);
#pragma unroll
    for (int mt = 0; mt < MT; ++mt)
      acc[mt] = __builtin_amdgcn_mfma_f32_16x16x32_bf16(a[mt][0], b2, acc[mt], 0, 0, 0);
#pragma unroll
    for (int mt = 0; mt < MT; ++mt)
      acc[mt] = __builtin_amdgcn_mfma_f32_16x16x32_bf16(a[mt][1], b3, acc[mt], 0, 0, 0);

    // fold into running argmin; C/D layout: col=lane&15, row=quad*4+reg
#pragma unroll
    for (int mt = 0; mt < MT; ++mt)
#pragma unroll
      for (int reg = 0; reg < 4; ++reg) {
        float dist = fmaf(-2.0f, acc[mt][reg], rzv[mt * 4 + reg] + en);
        int i = mt * 4 + reg;
        bool better = dist < bestd[i];  // strict <: ascending k keeps lowest
        bestk[i] = better ? mycode : bestk[i];
        bestd[i] = better ? dist : bestd[i];
      }
  }

  // publish per-lane candidates: per row, 16 col-classes x 4 waves
#pragma unroll
  for (int mt = 0; mt < MT; ++mt)
#pragma unroll
    for (int reg = 0; reg < 4; ++reg) {
      int row = mt * 16 + quad * 4 + reg;
      candd[wav][row][col] = bestd[mt * 4 + reg];
      candk[wav][row][col] = bestk[mt * 4 + reg];
    }
  __syncthreads();

  // ---- final per-row argmin, parallel across all 4 waves (8 rows each),
  // top-2 + exact fp32 recheck (R3 arithmetic) when margin < 1e-5
  // (provably safe: split-dot vs fp32-dot differ <4e-7; np grid quantum
  // at dist~64 is 7.6e-6).
  if (lane < ROWS / 4) {
    const int row = wav * (ROWS / 4) + lane;
    float bd1 = 3.4e38f, bd2 = 3.4e38f;
    int bk1 = 0x7fffffff, bk2 = 0x7fffffff;
#pragma unroll
    for (int w = 0; w < 4; ++w)
      for (int c = 0; c < 16; ++c) {
        float dv = candd[w][row][c];
        int kv = candk[w][row][c];
        bool b1 = (dv < bd1) || (dv == bd1 && kv < bk1);
        bool b2 = (dv < bd2) || (dv == bd2 && kv < bk2);
        if (b1) {
          bd2 = bd1; bk2 = bk1;
          bd1 = dv; bk1 = kv;
        } else if (b2) {
          bd2 = dv; bk2 = kv;
        }
      }
    if (bd2 - bd1 < 1e-5f) {
      // exact fp32 recompute, bit-identical to the R3 kernel's arithmetic
      const int grow = rowbase + row;
      const float4* zp = (const float4*)(z + (size_t)grow * D);
      float s0 = 0.f, s1 = 0.f, s2 = 0.f, s3 = 0.f;
#pragma unroll
      for (int i = 0; i < 16; ++i) {
        float4 v = zp[i];
        s0 = fmaf(v.x, v.x, s0);
        s1 = fmaf(v.y, v.y, s1);
        s2 = fmaf(v.z, v.z, s2);
        s3 = fmaf(v.w, v.w, s3);
      }
      const float rzx = (s0 + s1) + (s2 + s3);
      float dx[2];
      int kk[2] = {bk1, bk2};
#pragma unroll
      for (int c = 0; c < 2; ++c) {
        const float4* e4 = (const float4*)(cb + (size_t)kk[c] * D);
        float d0 = 0.f, d1 = 0.f, d2 = 0.f, d3 = 0.f;
#pragma unroll
        for (int i = 0; i < 16; ++i) {
          float4 v = e4[i];
          float4 zv = zp[i];
          d0 = fmaf(zv.x, v.x, d0);
          d1 = fmaf(zv.y, v.y, d1);
          d2 = fmaf(zv.z, v.z, d2);
          d3 = fmaf(zv.w, v.w, d3);
        }
        float dot = (d0 + d1) + (d2 + d3);
        dx[c] = (rzx + cbn[kk[c]]) - 2.0f * dot;
      }
      if ((dx[1] < dx[0]) || (dx[1] == dx[0] && bk2 < bk1)) bk1 = bk2;
    }
    skf[row] = bk1;
    out_idx[rowbase + row] = (float)bk1;
    atomicAdd(&hist[bk1], 1u);
  }
  __syncthreads();

  // ---- epilogue: quantized write (exact fp32 codebook rows) + loss partial
  float lsum = 0.f;
#pragma unroll
  for (int it = 0; it < ROWS / 16; ++it) {
    int f4 = it * 256 + tid;
    int r = f4 >> 4;
    int c4 = (f4 & 15) * 4;
    int bk = skf[r];
    const float4 q = *(const float4*)(cb + (size_t)bk * D + c4);
    const int grow = rowbase + r;
    const float4 zv = *(const float4*)(z + (size_t)grow * D + c4);
    *(float4*)(out_q + (size_t)grow * D + c4) = q;
    float ax = q.x - zv.x, ay = q.y - zv.y, az = q.z - zv.z, aw = q.w - zv.w;
    lsum += ax * ax + ay * ay + az * az + aw * aw;
  }
#pragma unroll
  for (int off = 32; off > 0; off >>= 1) lsum += __shfl_down(lsum, off, 64);
  if (lane == 0) swav[wav] = lsum;
  __syncthreads();
  if (tid == 0) {
    atomicAdd(loss_acc, (swav[0] + swav[1]) + (swav[2] + swav[3]));
  }
}

__global__ __launch_bounds__(1024) void vq_final(
    const unsigned int* __restrict__ hist, const float* __restrict__ loss_acc,
    float* __restrict__ out_loss, float* __restrict__ out_perp, float inv_n,
    float inv_nd) {
  __shared__ float part[16];
  const int t = threadIdx.x;
  const int lane = t & 63;
  const int wav = t >> 6;
  float p = (float)hist[t] * inv_n;
  float v = p * logf(p + 1e-10f);
#pragma unroll
  for (int off = 32; off > 0; off >>= 1) v += __shfl_down(v, off, 64);
  if (lane == 0) part[wav] = v;
  __syncthreads();
  if (t == 0) {
    float s = 0.f;
#pragma unroll
    for (int j = 0; j < 16; ++j) s += part[j];
    *out_perp = expf(-s);
    // q_latent + 0.25*e_latent, both numerically mean((q-z)^2)
    *out_loss = 1.25f * loss_acc[0] * inv_nd;
  }
}

extern "C" void kernel_launch(void* const* d_in, const int* in_sizes, int n_in,
                              void* d_out, int out_size, void* d_ws,
                              size_t ws_size, hipStream_t stream) {
  (void)n_in;
  (void)out_size;
  (void)ws_size;
  const float* z = (const float*)d_in[0];
  const float* cb = (const float*)d_in[1];
  const int N = in_sizes[0] / D;  // 32768

  // Output layout (flat float32, reference return order):
  float* out_q = (float*)d_out;                     // N*D
  float* out_loss = (float*)d_out + (size_t)N * D;  // 1
  float* out_idx = out_loss + 1;                    // N
  float* out_perp = out_idx + N;                    // 1

  // Workspace (floats): hist[1024] @0, loss_acc @1024, cbn[1024] @1040,
  // bsplit (short[1024*128]) @ float-idx 2064 (byte 8256, 16B-aligned).
  unsigned int* hist = (unsigned int*)d_ws;
  float* loss_acc = (float*)d_ws + 1024;
  float* cbn = (float*)d_ws + 1040;
  unsigned short* bsplit = (unsigned short*)((float*)d_ws + 2064);

  vq_prep<<<dim3(KC / 256), dim3(256), 0, stream>>>(cb, bsplit, cbn, hist,
                                                    loss_acc);
  vq_main<<<dim3(N / ROWS), dim3(256), 0, stream>>>(z, bsplit, cbn, cb, out_q,
                                                    out_idx, hist, loss_acc);
  vq_final<<<dim3(1), dim3(1024), 0, stream>>>(
      hist, loss_acc, out_loss, out_perp, 1.0f / (float)N,
      1.0f / ((float)N * (float)D));
}

// Round 9
// 102.694 us; speedup vs baseline: 1.1289x; 1.1289x over previous
//
#include <hip/hip_runtime.h>
#include <math.h>

// VQ-VAE vector quantizer for MI355X (gfx950).
// z: [32768, 64] fp32, codebook: [1024, 64] fp32.
// Outputs (flat float32, concatenated): quantized_st [32768*64], vq_loss [1],
// indices [32768] (as float), perplexity [1].
//
// R9: R4..R8 all pinned at ~40 us vq_main with ~73% idle; occupancy raises
// fail (compiler remats A-frags below MT=4 pressure), prefetch/tail tweaks
// neutral. Remaining unexplained wall == the 32768 device atomicAdds into
// hist[1024]: with this problem's codebook ~uniform(-1/1024,1/1024) all codes
// sit near the origin and usage concentrates on few codes -> same-address
// global atomics serialize at the TCC (~32768 x 3 cyc ~= 40 us). Fix: per-
// block LDS histogram + deduplicated flush (<=64 global atomics per block,
// one per DISTINCT code). Everything else identical to R7.

#define D 64
#define KC 1024
#define MT 4              // 16-row m-tiles per wave
#define ROWS (MT * 16)    // 64 rows per block

typedef short short8 __attribute__((ext_vector_type(8)));
typedef short short4v __attribute__((ext_vector_type(4)));
typedef float f32x4 __attribute__((ext_vector_type(4)));

__device__ __forceinline__ unsigned short f2bf(float x) {
  unsigned int u = __float_as_uint(x);
  unsigned int r = (u + 0x7fffu + ((u >> 16) & 1u)) >> 16;
  return (unsigned short)r;
}
__device__ __forceinline__ float bf2f(unsigned short h) {
  return __uint_as_float((unsigned int)h << 16);
}

// Precompute: exact fp32 code norms, split-bf16 codebook
// bsplit[k][128] = [e_hi(64) | e_lo(64)], zero hist/loss.
__global__ __launch_bounds__(256) void vq_prep(
    const float* __restrict__ cb, unsigned short* __restrict__ bsplit,
    float* __restrict__ cbn, unsigned int* __restrict__ hist,
    float* __restrict__ loss_acc) {
  const int k = blockIdx.x * 256 + threadIdx.x;  // 0..1023
  const float4* e = (const float4*)(cb + (size_t)k * D);
  unsigned short* bp = bsplit + (size_t)k * 128;
  float s0 = 0.f, s1 = 0.f, s2 = 0.f, s3 = 0.f;
#pragma unroll
  for (int i = 0; i < 16; ++i) {
    float4 v = e[i];
    s0 = fmaf(v.x, v.x, s0);
    s1 = fmaf(v.y, v.y, s1);
    s2 = fmaf(v.z, v.z, s2);
    s3 = fmaf(v.w, v.w, s3);
    unsigned short h0 = f2bf(v.x), h1 = f2bf(v.y), h2 = f2bf(v.z), h3 = f2bf(v.w);
    short4v hv = {(short)h0, (short)h1, (short)h2, (short)h3};
    short4v lv = {(short)f2bf(v.x - bf2f(h0)), (short)f2bf(v.y - bf2f(h1)),
                  (short)f2bf(v.z - bf2f(h2)), (short)f2bf(v.w - bf2f(h3))};
    *(short4v*)(bp + i * 4) = hv;
    *(short4v*)(bp + 64 + i * 4) = lv;
  }
  cbn[k] = (s0 + s1) + (s2 + s3);
  hist[k] = 0u;
  if (k == 0) loss_acc[0] = 0.f;
}

__global__ __launch_bounds__(256, 2) void vq_main(
    const float* __restrict__ z, const unsigned short* __restrict__ bsplit,
    const float* __restrict__ cbn, const float* __restrict__ cb,
    float* __restrict__ out_q, float* __restrict__ out_idx,
    unsigned int* __restrict__ hist, float* __restrict__ loss_acc) {
  // A' split-bf16 z tile: [64 rows][128 inner], stride 136 (bank-skew).
  __shared__ unsigned short Ash[ROWS * 136];
  __shared__ float srzp[ROWS * 16];
  __shared__ float srz[ROWS];
  __shared__ float candd[4][ROWS][17];  // +1 pad
  __shared__ int candk[4][ROWS][17];
  __shared__ int skf[ROWS];
  __shared__ float swav[4];
  __shared__ unsigned int lhist[KC];  // per-block histogram (dedup atomics)

  const int tid = threadIdx.x;
  const int lane = tid & 63;
  const int wav = tid >> 6;
  const int quad = lane >> 4;
  const int col = lane & 15;
  const int rowbase = blockIdx.x * ROWS;

  // ---- prologue: load z tile (coalesced), split to bf16 hi/lo, row norms
  const float4* z4 = (const float4*)(z + (size_t)rowbase * D);
#pragma unroll
  for (int it = 0; it < ROWS / 16; ++it) {
    int f4 = it * 256 + tid;  // row*16 + (c4/4)
    int row = f4 >> 4, c4 = (f4 & 15) * 4;
    float4 v = z4[f4];
    srzp[f4] = ((v.x * v.x + v.y * v.y) + (v.z * v.z + v.w * v.w));
    unsigned short h0 = f2bf(v.x), h1 = f2bf(v.y), h2 = f2bf(v.z), h3 = f2bf(v.w);
    short4v hv = {(short)h0, (short)h1, (short)h2, (short)h3};
    short4v lv = {(short)f2bf(v.x - bf2f(h0)), (short)f2bf(v.y - bf2f(h1)),
                  (short)f2bf(v.z - bf2f(h2)), (short)f2bf(v.w - bf2f(h3))};
    *(short4v*)&Ash[row * 136 + c4] = hv;
    *(short4v*)&Ash[row * 136 + 64 + c4] = lv;
  }
#pragma unroll
  for (int j = 0; j < KC / 256; ++j) lhist[tid + 256 * j] = 0u;
  __syncthreads();
  if (tid < ROWS) {
    float s = 0.f;
#pragma unroll
    for (int i = 0; i < 16; ++i) s += srzp[tid * 16 + i];
    srz[tid] = s;
  }
  __syncthreads();

  // rz per (m-tile, reg): lane holds C rows mt*16 + quad*4 + reg
  float rzv[MT * 4];
#pragma unroll
  for (int mt = 0; mt < MT; ++mt)
#pragma unroll
    for (int reg = 0; reg < 4; ++reg)
      rzv[mt * 4 + reg] = srz[mt * 16 + quad * 4 + reg];

  // A fragments in registers: a[mt][{hi0,hi1,lo0,lo1}], 8 bf16 each.
  // A-operand layout: lane holds A[m = col][k = quad*8 + j].
  short8 a[MT][4];
#pragma unroll
  for (int mt = 0; mt < MT; ++mt) {
    const unsigned short* base = &Ash[(mt * 16 + col) * 136 + quad * 8];
    a[mt][0] = *(const short8*)(base + 0);    // z_hi k 0..31
    a[mt][1] = *(const short8*)(base + 32);   // z_hi k 32..63
    a[mt][2] = *(const short8*)(base + 64);   // z_lo k 0..31
    a[mt][3] = *(const short8*)(base + 96);   // z_lo k 32..63
  }

  float bestd[MT * 4];
  int bestk[MT * 4];
#pragma unroll
  for (int i = 0; i < MT * 4; ++i) {
    bestd[i] = 3.4e38f;
    bestk[i] = 0;
  }

  // Each wave scans 256 codes as 8 iterations x 2 sub-tiles of 16 codes,
  // next iteration's B-fragments prefetched into registers.
  const int k0 = wav * 256;
  short8 p0[4], p1[4];
  float pe0, pe1;
  {
    const unsigned short* b0p = bsplit + (size_t)(k0 + col) * 128 + quad * 8;
    p0[0] = *(const short8*)(b0p + 0);
    p0[1] = *(const short8*)(b0p + 32);
    p0[2] = *(const short8*)(b0p + 64);
    p0[3] = *(const short8*)(b0p + 96);
    pe0 = cbn[k0 + col];
    const unsigned short* b1p = bsplit + (size_t)(k0 + 16 + col) * 128 + quad * 8;
    p1[0] = *(const short8*)(b1p + 0);
    p1[1] = *(const short8*)(b1p + 32);
    p1[2] = *(const short8*)(b1p + 64);
    p1[3] = *(const short8*)(b1p + 96);
    pe1 = cbn[k0 + 16 + col];
  }

  for (int it = 0; it < 8; ++it) {
    const short8 c00 = p0[0], c01 = p0[1], c02 = p0[2], c03 = p0[3];
    const short8 c10 = p1[0], c11 = p1[1], c12 = p1[2], c13 = p1[3];
    const float ce0 = pe0, ce1 = pe1;
    const int kbase = k0 + it * 32;
    if (it < 7) {
      const unsigned short* n0 =
          bsplit + (size_t)(kbase + 32 + col) * 128 + quad * 8;
      p0[0] = *(const short8*)(n0 + 0);
      p0[1] = *(const short8*)(n0 + 32);
      p0[2] = *(const short8*)(n0 + 64);
      p0[3] = *(const short8*)(n0 + 96);
      pe0 = cbn[kbase + 32 + col];
      const unsigned short* n1 =
          bsplit + (size_t)(kbase + 48 + col) * 128 + quad * 8;
      p1[0] = *(const short8*)(n1 + 0);
      p1[1] = *(const short8*)(n1 + 32);
      p1[2] = *(const short8*)(n1 + 64);
      p1[3] = *(const short8*)(n1 + 96);
      pe1 = cbn[kbase + 48 + col];
    }

    // ---- sub-tile 0 (codes kbase + col)
    {
      f32x4 acc[MT];
#pragma unroll
      for (int mt = 0; mt < MT; ++mt) acc[mt] = {0.f, 0.f, 0.f, 0.f};
#pragma unroll
      for (int mt = 0; mt < MT; ++mt)
        acc[mt] = __builtin_amdgcn_mfma_f32_16x16x32_bf16(a[mt][0], c00, acc[mt], 0, 0, 0);
#pragma unroll
      for (int mt = 0; mt < MT; ++mt)
        acc[mt] = __builtin_amdgcn_mfma_f32_16x16x32_bf16(a[mt][1], c01, acc[mt], 0, 0, 0);
#pragma unroll
      for (int mt = 0; mt < MT; ++mt)
        acc[mt] = __builtin_amdgcn_mfma_f32_16x16x32_bf16(a[mt][2], c00, acc[mt], 0, 0, 0);
#pragma unroll
      for (int mt = 0; mt < MT; ++mt)
        acc[mt] = __builtin_amdgcn_mfma_f32_16x16x32_bf16(a[mt][3], c01, acc[mt], 0, 0, 0);
#pragma unroll
      for (int mt = 0; mt < MT; ++mt)
        acc[mt] = __builtin_amdgcn_mfma_f32_16x16x32_bf16(a[mt][0], c02, acc[mt], 0, 0, 0);
#pragma unroll
      for (int mt = 0; mt < MT; ++mt)
        acc[mt] = __builtin_amdgcn_mfma_f32_16x16x32_bf16(a[mt][1], c03, acc[mt], 0, 0, 0);
      const int mycode = kbase + col;
#pragma unroll
      for (int mt = 0; mt < MT; ++mt)
#pragma unroll
        for (int reg = 0; reg < 4; ++reg) {
          float dist = fmaf(-2.0f, acc[mt][reg], rzv[mt * 4 + reg] + ce0);
          int i = mt * 4 + reg;
          bool better = dist < bestd[i];
          bestk[i] = better ? mycode : bestk[i];
          bestd[i] = better ? dist : bestd[i];
        }
    }
    // ---- sub-tile 1 (codes kbase + 16 + col)
    {
      f32x4 acc[MT];
#pragma unroll
      for (int mt = 0; mt < MT; ++mt) acc[mt] = {0.f, 0.f, 0.f, 0.f};
#pragma unroll
      for (int mt = 0; mt < MT; ++mt)
        acc[mt] = __builtin_amdgcn_mfma_f32_16x16x32_bf16(a[mt][0], c10, acc[mt], 0, 0, 0);
#pragma unroll
      for (int mt = 0; mt < MT; ++mt)
        acc[mt] = __builtin_amdgcn_mfma_f32_16x16x32_bf16(a[mt][1], c11, acc[mt], 0, 0, 0);
#pragma unroll
      for (int mt = 0; mt < MT; ++mt)
        acc[mt] = __builtin_amdgcn_mfma_f32_16x16x32_bf16(a[mt][2], c10, acc[mt], 0, 0, 0);
#pragma unroll
      for (int mt = 0; mt < MT; ++mt)
        acc[mt] = __builtin_amdgcn_mfma_f32_16x16x32_bf16(a[mt][3], c11, acc[mt], 0, 0, 0);
#pragma unroll
      for (int mt = 0; mt < MT; ++mt)
        acc[mt] = __builtin_amdgcn_mfma_f32_16x16x32_bf16(a[mt][0], c12, acc[mt], 0, 0, 0);
#pragma unroll
      for (int mt = 0; mt < MT; ++mt)
        acc[mt] = __builtin_amdgcn_mfma_f32_16x16x32_bf16(a[mt][1], c13, acc[mt], 0, 0, 0);
      const int mycode = kbase + 16 + col;
#pragma unroll
      for (int mt = 0; mt < MT; ++mt)
#pragma unroll
        for (int reg = 0; reg < 4; ++reg) {
          float dist = fmaf(-2.0f, acc[mt][reg], rzv[mt * 4 + reg] + ce1);
          int i = mt * 4 + reg;
          bool better = dist < bestd[i];
          bestk[i] = better ? mycode : bestk[i];
          bestd[i] = better ? dist : bestd[i];
        }
    }
  }

  // publish per-lane candidates: per row, 16 col-classes x 4 waves
#pragma unroll
  for (int mt = 0; mt < MT; ++mt)
#pragma unroll
    for (int reg = 0; reg < 4; ++reg) {
      int row = mt * 16 + quad * 4 + reg;
      candd[wav][row][col] = bestd[mt * 4 + reg];
      candk[wav][row][col] = bestk[mt * 4 + reg];
    }
  __syncthreads();

  // ---- final per-row argmin, parallel across all 4 waves (16 rows each),
  // top-2 + exact fp32 recheck (R3 arithmetic) when margin < 1e-5
  // (provably safe: split-dot vs fp32-dot differ <4e-7; np grid quantum
  // at dist~64 is 7.6e-6).
  if (lane < 16) {
    const int row = wav * 16 + lane;
    float bd1 = 3.4e38f, bd2 = 3.4e38f;
    int bk1 = 0x7fffffff, bk2 = 0x7fffffff;
#pragma unroll
    for (int w = 0; w < 4; ++w)
      for (int c = 0; c < 16; ++c) {
        float dv = candd[w][row][c];
        int kv = candk[w][row][c];
        bool b1 = (dv < bd1) || (dv == bd1 && kv < bk1);
        bool b2 = (dv < bd2) || (dv == bd2 && kv < bk2);
        if (b1) {
          bd2 = bd1; bk2 = bk1;
          bd1 = dv; bk1 = kv;
        } else if (b2) {
          bd2 = dv; bk2 = kv;
        }
      }
    if (bd2 - bd1 < 1e-5f) {
      // exact fp32 recompute, bit-identical to the R3 kernel's arithmetic
      const int grow = rowbase + row;
      const float4* zp = (const float4*)(z + (size_t)grow * D);
      float s0 = 0.f, s1 = 0.f, s2 = 0.f, s3 = 0.f;
#pragma unroll
      for (int i = 0; i < 16; ++i) {
        float4 v = zp[i];
        s0 = fmaf(v.x, v.x, s0);
        s1 = fmaf(v.y, v.y, s1);
        s2 = fmaf(v.z, v.z, s2);
        s3 = fmaf(v.w, v.w, s3);
      }
      const float rzx = (s0 + s1) + (s2 + s3);
      float dx[2];
      int kk[2] = {bk1, bk2};
#pragma unroll
      for (int c = 0; c < 2; ++c) {
        const float4* e4 = (const float4*)(cb + (size_t)kk[c] * D);
        float d0 = 0.f, d1 = 0.f, d2 = 0.f, d3 = 0.f;
#pragma unroll
        for (int i = 0; i < 16; ++i) {
          float4 v = e4[i];
          float4 zv = zp[i];
          d0 = fmaf(zv.x, v.x, d0);
          d1 = fmaf(zv.y, v.y, d1);
          d2 = fmaf(zv.z, v.z, d2);
          d3 = fmaf(zv.w, v.w, d3);
        }
        float dot = (d0 + d1) + (d2 + d3);
        dx[c] = (rzx + cbn[kk[c]]) - 2.0f * dot;
      }
      if ((dx[1] < dx[0]) || (dx[1] == dx[0] && bk2 < bk1)) bk1 = bk2;
    }
    skf[row] = bk1;
    out_idx[rowbase + row] = (float)bk1;
    atomicAdd(&lhist[bk1], 1u);  // LDS atomic: block-local, no TCC serialization
  }
  __syncthreads();

  // ---- flush per-block histogram: one GLOBAL atomic per DISTINCT code
  // (<=64 per block; removes the same-address TCC serialization of 32768
  // per-row device atomics).
#pragma unroll
  for (int j = 0; j < KC / 256; ++j) {
    unsigned int c = lhist[tid + 256 * j];
    if (c) atomicAdd(&hist[tid + 256 * j], c);
  }

  // ---- epilogue: quantized write (exact fp32 codebook rows) + loss partial
  float lsum = 0.f;
#pragma unroll
  for (int it = 0; it < ROWS / 16; ++it) {
    int f4 = it * 256 + tid;
    int r = f4 >> 4;
    int c4 = (f4 & 15) * 4;
    int bk = skf[r];
    const float4 q = *(const float4*)(cb + (size_t)bk * D + c4);
    const int grow = rowbase + r;
    const float4 zv = *(const float4*)(z + (size_t)grow * D + c4);
    *(float4*)(out_q + (size_t)grow * D + c4) = q;
    float ax = q.x - zv.x, ay = q.y - zv.y, az = q.z - zv.z, aw = q.w - zv.w;
    lsum += ax * ax + ay * ay + az * az + aw * aw;
  }
#pragma unroll
  for (int off = 32; off > 0; off >>= 1) lsum += __shfl_down(lsum, off, 64);
  if (lane == 0) swav[wav] = lsum;
  __syncthreads();
  if (tid == 0) {
    atomicAdd(loss_acc, (swav[0] + swav[1]) + (swav[2] + swav[3]));
  }
}

__global__ __launch_bounds__(1024) void vq_final(
    const unsigned int* __restrict__ hist, const float* __restrict__ loss_acc,
    float* __restrict__ out_loss, float* __restrict__ out_perp, float inv_n,
    float inv_nd) {
  __shared__ float part[16];
  const int t = threadIdx.x;
  const int lane = t & 63;
  const int wav = t >> 6;
  float p = (float)hist[t] * inv_n;
  float v = p * logf(p + 1e-10f);
#pragma unroll
  for (int off = 32; off > 0; off >>= 1) v += __shfl_down(v, off, 64);
  if (lane == 0) part[wav] = v;
  __syncthreads();
  if (t == 0) {
    float s = 0.f;
#pragma unroll
    for (int j = 0; j < 16; ++j) s += part[j];
    *out_perp = expf(-s);
    // q_latent + 0.25*e_latent, both numerically mean((q-z)^2)
    *out_loss = 1.25f * loss_acc[0] * inv_nd;
  }
}

extern "C" void kernel_launch(void* const* d_in, const int* in_sizes, int n_in,
                              void* d_out, int out_size, void* d_ws,
                              size_t ws_size, hipStream_t stream) {
  (void)n_in;
  (void)out_size;
  (void)ws_size;
  const float* z = (const float*)d_in[0];
  const float* cb = (const float*)d_in[1];
  const int N = in_sizes[0] / D;  // 32768

  // Output layout (flat float32, reference return order):
  float* out_q = (float*)d_out;                     // N*D
  float* out_loss = (float*)d_out + (size_t)N * D;  // 1
  float* out_idx = out_loss + 1;                    // N
  float* out_perp = out_idx + N;                    // 1

  // Workspace (floats): hist[1024] @0, loss_acc @1024, cbn[1024] @1040,
  // bsplit (short[1024*128]) @ float-idx 2064 (byte 8256, 16B-aligned).
  unsigned int* hist = (unsigned int*)d_ws;
  float* loss_acc = (float*)d_ws + 1024;
  float* cbn = (float*)d_ws + 1040;
  unsigned short* bsplit = (unsigned short*)((float*)d_ws + 2064);

  vq_prep<<<dim3(KC / 256), dim3(256), 0, stream>>>(cb, bsplit, cbn, hist,
                                                    loss_acc);
  vq_main<<<dim3(N / ROWS), dim3(256), 0, stream>>>(z, bsplit, cbn, cb, out_q,
                                                    out_idx, hist, loss_acc);
  vq_final<<<dim3(1), dim3(1024), 0, stream>>>(
      hist, loss_acc, out_loss, out_perp, 1.0f / (float)N,
      1.0f / ((float)N * (float)D));
}

// Round 10
// 102.365 us; speedup vs baseline: 1.1325x; 1.0032x over previous
//
#include <hip/hip_runtime.h>
#include <math.h>

// VQ-VAE vector quantizer for MI355X (gfx950).
// z: [32768, 64] fp32, codebook: [1024, 64] fp32.
// Outputs (flat float32, concatenated): quantized_st [32768*64], vq_loss [1],
// indices [32768] (as float), perplexity [1].
//
// R10: R4..R9 pinned at ~38 us vq_main, ~75% idle; every tweak (prefetch,
// occupancy, tail, atomics) neutral or worse. Common structural feature of
// all slow variants: K-loop B-operand via per-lane GLOBAL gathers (latency/
// queuing invisible to FETCH_SIZE, exposed at 2 waves/SIMD). R10 restructures
// to the proven m97/R2 shape: double-buffered LDS B-tiles (32 codes, 8.4 KB,
// stride-33 chunk layout -> conflict-free writes AND reads), each wave owns
// 16 rows and scans all 1024 codes -> no cross-wave reduction; per-lane
// exact top-2 + shuffle butterfly; LDS-pipe floor ~10-12 us.
// Numerics: 3-term split-bf16 + exact fp32 recheck (margin 1e-5), unchanged.

#define D 64
#define KC 1024
#define ROWS 64           // rows per block (4 waves x 16 rows)
#define TC 32             // codes per LDS tile
#define NT (KC / TC)      // 32 tiles
#define BCH 33            // chunk stride (16B chunks) for bank-conflict-free B

typedef short short8 __attribute__((ext_vector_type(8)));
typedef short short4v __attribute__((ext_vector_type(4)));
typedef float f32x4 __attribute__((ext_vector_type(4)));

__device__ __forceinline__ unsigned short f2bf(float x) {
  unsigned int u = __float_as_uint(x);
  unsigned int r = (u + 0x7fffu + ((u >> 16) & 1u)) >> 16;
  return (unsigned short)r;
}
__device__ __forceinline__ float bf2f(unsigned short h) {
  return __uint_as_float((unsigned int)h << 16);
}

// Precompute: exact fp32 code norms, split-bf16 codebook
// bsplit[k][128] = [e_hi(64) | e_lo(64)], zero hist/loss.
__global__ __launch_bounds__(256) void vq_prep(
    const float* __restrict__ cb, unsigned short* __restrict__ bsplit,
    float* __restrict__ cbn, unsigned int* __restrict__ hist,
    float* __restrict__ loss_acc) {
  const int k = blockIdx.x * 256 + threadIdx.x;  // 0..1023
  const float4* e = (const float4*)(cb + (size_t)k * D);
  unsigned short* bp = bsplit + (size_t)k * 128;
  float s0 = 0.f, s1 = 0.f, s2 = 0.f, s3 = 0.f;
#pragma unroll
  for (int i = 0; i < 16; ++i) {
    float4 v = e[i];
    s0 = fmaf(v.x, v.x, s0);
    s1 = fmaf(v.y, v.y, s1);
    s2 = fmaf(v.z, v.z, s2);
    s3 = fmaf(v.w, v.w, s3);
    unsigned short h0 = f2bf(v.x), h1 = f2bf(v.y), h2 = f2bf(v.z), h3 = f2bf(v.w);
    short4v hv = {(short)h0, (short)h1, (short)h2, (short)h3};
    short4v lv = {(short)f2bf(v.x - bf2f(h0)), (short)f2bf(v.y - bf2f(h1)),
                  (short)f2bf(v.z - bf2f(h2)), (short)f2bf(v.w - bf2f(h3))};
    *(short4v*)(bp + i * 4) = hv;
    *(short4v*)(bp + 64 + i * 4) = lv;
  }
  cbn[k] = (s0 + s1) + (s2 + s3);
  hist[k] = 0u;
  if (k == 0) loss_acc[0] = 0.f;
}

__global__ __launch_bounds__(256, 2) void vq_main(
    const float* __restrict__ z, const unsigned short* __restrict__ bsplit,
    const float* __restrict__ cbn, const float* __restrict__ cb,
    float* __restrict__ out_q, float* __restrict__ out_idx,
    unsigned int* __restrict__ hist, float* __restrict__ loss_acc) {
  // A' split-bf16 z tile: [64 rows][128 inner], stride 136 (bank-skew).
  __shared__ __align__(16) unsigned short Ash[ROWS * 136];
  // B double buffer: 16 chunk-rows x 33 (stride) 16B chunks each.
  __shared__ __align__(16) unsigned short Bsh[2][16 * BCH * 8];
  __shared__ float scbn[KC];
  __shared__ float srzp[ROWS * 16];
  __shared__ float srz[ROWS];
  __shared__ int skf[ROWS];
  __shared__ float swav[4];
  __shared__ unsigned int lhist[KC];

  const int tid = threadIdx.x;
  const int lane = tid & 63;
  const int wav = tid >> 6;
  const int quad = lane >> 4;
  const int col = lane & 15;
  const int rowbase = blockIdx.x * ROWS;

  // ---- prologue: z tile -> Ash (split bf16) + row norms + cbn -> LDS +
  //      stage B tile 0 + zero lhist
  const float4* z4 = (const float4*)(z + (size_t)rowbase * D);
#pragma unroll
  for (int it = 0; it < 4; ++it) {
    int f4 = it * 256 + tid;  // row*16 + (c4/4)
    int row = f4 >> 4, c4 = (f4 & 15) * 4;
    float4 v = z4[f4];
    srzp[f4] = ((v.x * v.x + v.y * v.y) + (v.z * v.z + v.w * v.w));
    unsigned short h0 = f2bf(v.x), h1 = f2bf(v.y), h2 = f2bf(v.z), h3 = f2bf(v.w);
    short4v hv = {(short)h0, (short)h1, (short)h2, (short)h3};
    short4v lv = {(short)f2bf(v.x - bf2f(h0)), (short)f2bf(v.y - bf2f(h1)),
                  (short)f2bf(v.z - bf2f(h2)), (short)f2bf(v.w - bf2f(h3))};
    *(short4v*)&Ash[row * 136 + c4] = hv;
    *(short4v*)&Ash[row * 136 + 64 + c4] = lv;
  }
  *(float4*)&scbn[tid * 4] = *(const float4*)&cbn[tid * 4];
#pragma unroll
  for (int j = 0; j < KC / 256; ++j) lhist[tid + 256 * j] = 0u;

  // stage tile 0: thread t moves global chunks t and t+256 of the tile.
  // chunk g: code k=g>>4, plane-chunk jj=g&15; LDS slot = jj*BCH + k.
  const int cslot = (tid & 15) * BCH + (tid >> 4);  // slot for chunk tid
  {
    const size_t off = (size_t)(tid >> 4) * 128 + (size_t)(tid & 15) * 8;
    short8 s0 = *(const short8*)(bsplit + off);
    short8 s1 = *(const short8*)(bsplit + off + 2048);  // +16 codes
    *(short8*)&Bsh[0][cslot * 8] = s0;
    *(short8*)&Bsh[0][(cslot + 16) * 8] = s1;
  }
  __syncthreads();
  if (tid < ROWS) {
    float s = 0.f;
#pragma unroll
    for (int i = 0; i < 16; ++i) s += srzp[tid * 16 + i];
    srz[tid] = s;
  }
  __syncthreads();

  // wave w owns block rows w*16..w*16+15. A-frags: lane holds A[m=col][k=quad*8+j]
  const unsigned short* abase = &Ash[(wav * 16 + col) * 136 + quad * 8];
  const short8 a0 = *(const short8*)(abase + 0);   // z_hi k 0..31
  const short8 a1 = *(const short8*)(abase + 32);  // z_hi k 32..63
  const short8 a2 = *(const short8*)(abase + 64);  // z_lo k 0..31
  const short8 a3 = *(const short8*)(abase + 96);  // z_lo k 32..63

  float rzv[4];
#pragma unroll
  for (int reg = 0; reg < 4; ++reg) rzv[reg] = srz[wav * 16 + quad * 4 + reg];

  // per-lane exact top-2 over this lane's code class (col mod 16)
  float b1d[4], b2d[4];
  int b1k[4], b2k[4];
#pragma unroll
  for (int i = 0; i < 4; ++i) {
    b1d[i] = 3.4e38f; b2d[i] = 3.4e38f;
    b1k[i] = 0x7fffffff; b2k[i] = 0x7fffffff;
  }

  // ---- K-loop: 32 tiles of 32 codes, double-buffered LDS
  for (int j = 0; j < NT; ++j) {
    const int kb = j * TC;
    const unsigned short* bcur = &Bsh[j & 1][0];
    // stage next tile: global -> regs (lands during this tile's compute)
    short8 st0, st1;
    if (j + 1 < NT) {
      const size_t off = (size_t)((j + 1) * TC + (tid >> 4)) * 128 +
                         (size_t)(tid & 15) * 8;
      st0 = *(const short8*)(bsplit + off);
      st1 = *(const short8*)(bsplit + off + 2048);
    }
    const float enA = scbn[kb + col];
    const float enB = scbn[kb + 16 + col];
    // B-frags: chain A = code col, chain B = code col+16.
    // frag i lives at chunk-row i*4+quad, slot = row*BCH + code.
    const short8 bA0 = *(const short8*)(bcur + ((0 + quad) * BCH + col) * 8);
    const short8 bA1 = *(const short8*)(bcur + ((4 + quad) * BCH + col) * 8);
    const short8 bA2 = *(const short8*)(bcur + ((8 + quad) * BCH + col) * 8);
    const short8 bA3 = *(const short8*)(bcur + ((12 + quad) * BCH + col) * 8);
    const short8 bB0 = *(const short8*)(bcur + ((0 + quad) * BCH + col + 16) * 8);
    const short8 bB1 = *(const short8*)(bcur + ((4 + quad) * BCH + col + 16) * 8);
    const short8 bB2 = *(const short8*)(bcur + ((8 + quad) * BCH + col + 16) * 8);
    const short8 bB3 = *(const short8*)(bcur + ((12 + quad) * BCH + col + 16) * 8);

    f32x4 accA = {0.f, 0.f, 0.f, 0.f}, accB = {0.f, 0.f, 0.f, 0.f};
    // 3-term split: hi.hi + lo.hi + hi.lo ; two independent chains (ILP 2)
    accA = __builtin_amdgcn_mfma_f32_16x16x32_bf16(a0, bA0, accA, 0, 0, 0);
    accB = __builtin_amdgcn_mfma_f32_16x16x32_bf16(a0, bB0, accB, 0, 0, 0);
    accA = __builtin_amdgcn_mfma_f32_16x16x32_bf16(a1, bA1, accA, 0, 0, 0);
    accB = __builtin_amdgcn_mfma_f32_16x16x32_bf16(a1, bB1, accB, 0, 0, 0);
    accA = __builtin_amdgcn_mfma_f32_16x16x32_bf16(a2, bA0, accA, 0, 0, 0);
    accB = __builtin_amdgcn_mfma_f32_16x16x32_bf16(a2, bB0, accB, 0, 0, 0);
    accA = __builtin_amdgcn_mfma_f32_16x16x32_bf16(a3, bA1, accA, 0, 0, 0);
    accB = __builtin_amdgcn_mfma_f32_16x16x32_bf16(a3, bB1, accB, 0, 0, 0);
    accA = __builtin_amdgcn_mfma_f32_16x16x32_bf16(a0, bA2, accA, 0, 0, 0);
    accB = __builtin_amdgcn_mfma_f32_16x16x32_bf16(a0, bB2, accB, 0, 0, 0);
    accA = __builtin_amdgcn_mfma_f32_16x16x32_bf16(a1, bA3, accA, 0, 0, 0);
    accB = __builtin_amdgcn_mfma_f32_16x16x32_bf16(a1, bB3, accB, 0, 0, 0);

    // fold with exact per-lane top-2; strict < + ascending scan keeps lowest k
#pragma unroll
    for (int reg = 0; reg < 4; ++reg) {
      {
        float d = fmaf(-2.0f, accA[reg], rzv[reg] + enA);
        int k = kb + col;
        bool w1 = d < b1d[reg];
        bool w2 = d < b2d[reg];
        b2d[reg] = w1 ? b1d[reg] : (w2 ? d : b2d[reg]);
        b2k[reg] = w1 ? b1k[reg] : (w2 ? k : b2k[reg]);
        b1d[reg] = w1 ? d : b1d[reg];
        b1k[reg] = w1 ? k : b1k[reg];
      }
      {
        float d = fmaf(-2.0f, accB[reg], rzv[reg] + enB);
        int k = kb + 16 + col;
        bool w1 = d < b1d[reg];
        bool w2 = d < b2d[reg];
        b2d[reg] = w1 ? b1d[reg] : (w2 ? d : b2d[reg]);
        b2k[reg] = w1 ? b1k[reg] : (w2 ? k : b2k[reg]);
        b1d[reg] = w1 ? d : b1d[reg];
        b1k[reg] = w1 ? k : b1k[reg];
      }
    }

    // commit staged regs to the other buffer, then barrier
    if (j + 1 < NT) {
      unsigned short* bn = &Bsh[(j + 1) & 1][0];
      *(short8*)&bn[cslot * 8] = st0;
      *(short8*)&bn[(cslot + 16) * 8] = st1;
    }
    __syncthreads();
  }

  // ---- cross-lane top-2 butterfly over the 16 col-classes (within quad group)
#pragma unroll
  for (int m = 1; m < 16; m <<= 1) {
#pragma unroll
    for (int reg = 0; reg < 4; ++reg) {
      float od1 = __shfl_xor(b1d[reg], m, 64);
      int ok1 = __shfl_xor(b1k[reg], m, 64);
      float od2 = __shfl_xor(b2d[reg], m, 64);
      int ok2 = __shfl_xor(b2k[reg], m, 64);
      bool fo = (od1 < b1d[reg]) || (od1 == b1d[reg] && ok1 < b1k[reg]);
      float w1 = fo ? od1 : b1d[reg];
      int wk1 = fo ? ok1 : b1k[reg];
      float l1 = fo ? b1d[reg] : od1;
      int lk1 = fo ? b1k[reg] : ok1;
      bool so = (od2 < b2d[reg]) || (od2 == b2d[reg] && ok2 < b2k[reg]);
      float m2 = so ? od2 : b2d[reg];
      int mk2 = so ? ok2 : b2k[reg];
      bool lw = (l1 < m2) || (l1 == m2 && lk1 < mk2);
      b1d[reg] = w1;
      b1k[reg] = wk1;
      b2d[reg] = lw ? l1 : m2;
      b2k[reg] = lw ? lk1 : mk2;
    }
  }

  // writer lanes: col<4 handles row = wav*16 + quad*4 + col (using reg=col)
  if (col < 4) {
    const int row = wav * 16 + quad * 4 + col;
    float bd1 = b1d[col], bd2 = b2d[col];
    int bk1 = b1k[col], bk2 = b2k[col];
    if (bd2 - bd1 < 1e-5f) {
      // exact fp32 recompute (R3 arithmetic) of the top-2 candidates
      const int grow = rowbase + row;
      const float4* zp = (const float4*)(z + (size_t)grow * D);
      float s0 = 0.f, s1 = 0.f, s2 = 0.f, s3 = 0.f;
#pragma unroll
      for (int i = 0; i < 16; ++i) {
        float4 v = zp[i];
        s0 = fmaf(v.x, v.x, s0);
        s1 = fmaf(v.y, v.y, s1);
        s2 = fmaf(v.z, v.z, s2);
        s3 = fmaf(v.w, v.w, s3);
      }
      const float rzx = (s0 + s1) + (s2 + s3);
      float dx[2];
      int kk[2] = {bk1, bk2};
#pragma unroll
      for (int c = 0; c < 2; ++c) {
        const float4* e4 = (const float4*)(cb + (size_t)kk[c] * D);
        float d0 = 0.f, d1 = 0.f, d2 = 0.f, d3 = 0.f;
#pragma unroll
        for (int i = 0; i < 16; ++i) {
          float4 v = e4[i];
          float4 zv = zp[i];
          d0 = fmaf(zv.x, v.x, d0);
          d1 = fmaf(zv.y, v.y, d1);
          d2 = fmaf(zv.z, v.z, d2);
          d3 = fmaf(zv.w, v.w, d3);
        }
        float dot = (d0 + d1) + (d2 + d3);
        dx[c] = (rzx + scbn[kk[c]]) - 2.0f * dot;
      }
      if ((dx[1] < dx[0]) || (dx[1] == dx[0] && bk2 < bk1)) bk1 = bk2;
    }
    skf[row] = bk1;
    out_idx[rowbase + row] = (float)bk1;
    atomicAdd(&lhist[bk1], 1u);
  }
  __syncthreads();

  // ---- flush per-block histogram: one global atomic per distinct code
#pragma unroll
  for (int j = 0; j < KC / 256; ++j) {
    unsigned int c = lhist[tid + 256 * j];
    if (c) atomicAdd(&hist[tid + 256 * j], c);
  }

  // ---- epilogue: quantized write (exact fp32 codebook rows) + loss partial
  float lsum = 0.f;
#pragma unroll
  for (int it = 0; it < 4; ++it) {
    int f4 = it * 256 + tid;
    int r = f4 >> 4;
    int c4 = (f4 & 15) * 4;
    int bk = skf[r];
    const float4 q = *(const float4*)(cb + (size_t)bk * D + c4);
    const int grow = rowbase + r;
    const float4 zv = *(const float4*)(z + (size_t)grow * D + c4);
    *(float4*)(out_q + (size_t)grow * D + c4) = q;
    float ax = q.x - zv.x, ay = q.y - zv.y, az = q.z - zv.z, aw = q.w - zv.w;
    lsum += ax * ax + ay * ay + az * az + aw * aw;
  }
#pragma unroll
  for (int off = 32; off > 0; off >>= 1) lsum += __shfl_down(lsum, off, 64);
  if (lane == 0) swav[wav] = lsum;
  __syncthreads();
  if (tid == 0) {
    atomicAdd(loss_acc, (swav[0] + swav[1]) + (swav[2] + swav[3]));
  }
}

__global__ __launch_bounds__(1024) void vq_final(
    const unsigned int* __restrict__ hist, const float* __restrict__ loss_acc,
    float* __restrict__ out_loss, float* __restrict__ out_perp, float inv_n,
    float inv_nd) {
  __shared__ float part[16];
  const int t = threadIdx.x;
  const int lane = t & 63;
  const int wav = t >> 6;
  float p = (float)hist[t] * inv_n;
  float v = p * logf(p + 1e-10f);
#pragma unroll
  for (int off = 32; off > 0; off >>= 1) v += __shfl_down(v, off, 64);
  if (lane == 0) part[wav] = v;
  __syncthreads();
  if (t == 0) {
    float s = 0.f;
#pragma unroll
    for (int j = 0; j < 16; ++j) s += part[j];
    *out_perp = expf(-s);
    // q_latent + 0.25*e_latent, both numerically mean((q-z)^2)
    *out_loss = 1.25f * loss_acc[0] * inv_nd;
  }
}

extern "C" void kernel_launch(void* const* d_in, const int* in_sizes, int n_in,
                              void* d_out, int out_size, void* d_ws,
                              size_t ws_size, hipStream_t stream) {
  (void)n_in;
  (void)out_size;
  (void)ws_size;
  const float* z = (const float*)d_in[0];
  const float* cb = (const float*)d_in[1];
  const int N = in_sizes[0] / D;  // 32768

  // Output layout (flat float32, reference return order):
  float* out_q = (float*)d_out;                     // N*D
  float* out_loss = (float*)d_out + (size_t)N * D;  // 1
  float* out_idx = out_loss + 1;                    // N
  float* out_perp = out_idx + N;                    // 1

  // Workspace (floats): hist[1024] @0, loss_acc @1024, cbn[1024] @1040,
  // bsplit (short[1024*128]) @ float-idx 2064 (byte 8256, 16B-aligned).
  unsigned int* hist = (unsigned int*)d_ws;
  float* loss_acc = (float*)d_ws + 1024;
  float* cbn = (float*)d_ws + 1040;
  unsigned short* bsplit = (unsigned short*)((float*)d_ws + 2064);

  vq_prep<<<dim3(KC / 256), dim3(256), 0, stream>>>(cb, bsplit, cbn, hist,
                                                    loss_acc);
  vq_main<<<dim3(N / ROWS), dim3(256), 0, stream>>>(z, bsplit, cbn, cb, out_q,
                                                    out_idx, hist, loss_acc);
  vq_final<<<dim3(1), dim3(1024), 0, stream>>>(
      hist, loss_acc, out_loss, out_perp, 1.0f / (float)N,
      1.0f / ((float)N * (float)D));
}